// Round 10
// baseline (671.827 us; speedup 1.0000x reference)
//
#include <hip/hip_runtime.h>
#include <math.h>

#define NBANDS 31
#define FT 257000

typedef __attribute__((ext_vector_type(8))) short bh8;
typedef __attribute__((ext_vector_type(4))) float f4;

__constant__ int d_bs[NBANDS] = {0,1,1,2,2,2,3,3,4,5,6,7,8,10,11,13,16,19,23,27,32,38,45,54,64,76,91,108,128,152,181};
__constant__ int d_be[NBANDS] = {2,3,3,3,4,4,5,6,7,8,9,11,12,14,17,20,24,28,33,39,46,55,65,77,92,109,129,153,182,216,257};

__device__ __forceinline__ unsigned short b16u(float v) {
  __bf16 h = (__bf16)v;
  return __builtin_bit_cast(unsigned short, h);
}
__device__ __forceinline__ unsigned pk2(float a, float b) {
  return (unsigned)b16u(a) | ((unsigned)b16u(b) << 16);
}
__device__ __forceinline__ float hann1(int i, int L) {
  return 0.5f - 0.5f * cosf(6.283185307179586f * (float)i / (float)L);
}

// ---- weight f32 -> bf16 prep, permuted into MFMA-fragment order ----
__global__ __launch_bounds__(256) void prep_w(
    const float* __restrict__ enc_w, const float* __restrict__ dec_w,
    const float* __restrict__ qw, const float* __restrict__ kw,
    const float* __restrict__ vw, const float* __restrict__ ow,
    unsigned short* __restrict__ w16) {
  const int stride = gridDim.x * blockDim.x;
  for (int i = blockIdx.x * blockDim.x + threadIdx.x; i < 513024; i += stride) {
    float v;
    if (i < 190464) {                      // enc: K=64, KT=2
      const int k = i / 6144, r = i - k * 6144;
      const int tile = r >> 9, li = r & 511;
      const int lane = li >> 3, j = li & 7;
      const int g = lane >> 4, n = lane & 15;
      const int mt = tile >> 1, kt = tile & 1;
      v = enc_w[k * 6144 + (mt * 16 + n) * 64 + kt * 32 + g * 8 + j];
    } else if (i < 476160) {               // dec: K=96, KT=3
      const int i2 = i - 190464;
      const int k = i2 / 9216, r = i2 - k * 9216;
      const int tile = r >> 9, li = r & 511;
      const int lane = li >> 3, j = li & 7;
      const int g = lane >> 4, n = lane & 15;
      const int mt = tile / 3, kt = tile - mt * 3;
      v = dec_w[k * 9216 + (mt * 16 + n) * 96 + kt * 32 + g * 8 + j];
    } else {                               // q,k,v,o
      const int i2 = i - 476160;
      const int a = i2 / 9216, r = i2 - a * 9216;
      const int tile = r >> 9, li = r & 511;
      const int lane = li >> 3, j = li & 7;
      const int g = lane >> 4, n = lane & 15;
      const int mt = tile / 3, kt = tile - mt * 3;
      const float* src = (a == 0) ? qw : (a == 1) ? kw : (a == 2) ? vw : ow;
      v = src[(mt * 16 + n) * 96 + kt * 32 + g * 8 + j];
    }
    w16[i] = b16u(v);
  }
}

__global__ __launch_bounds__(192) void qp_kernel(const float* __restrict__ doa,
                                                 const float* __restrict__ dqg_w,
                                                 const float* __restrict__ dqg_b,
                                                 float* __restrict__ gbuf) {
  const int k = blockIdx.x, b = blockIdx.y;
  const int tid = threadIdx.x;
  __shared__ float sdoa[36];
  if (tid < 36) sdoa[tid] = doa[b * 36 + tid];
  __syncthreads();
  const float* wr = dqg_w + (k * 192 + tid) * 36;
  float acc = dqg_b[k * 192 + tid];
  #pragma unroll
  for (int i = 0; i < 36; ++i) acc = fmaf(wr[i], sdoa[i], acc);
  if (tid < 96) acc += 1.0f;
  gbuf[(k * 4 + b) * 192 + tid] = acc;
}

// ---- per-f table: {k0, nb, winv, win0..win4} ----
__global__ __launch_bounds__(320) void tab_kernel(float* __restrict__ ftab) {
  const int f = blockIdx.x * blockDim.x + threadIdx.x;
  if (f >= 257) return;
  int k0 = 0; while (d_be[k0] <= f) ++k0;
  int k1 = k0; while (k1 < NBANDS && d_bs[k1] <= f) ++k1;
  float wsum = 0.f, wn[5];
  for (int k = k0; k < k1; ++k) {
    const float wv = hann1(f - d_bs[k], d_be[k] - d_bs[k]);
    wn[k - k0] = wv; wsum += wv;
  }
  float* o = ftab + f * 8;
  o[0] = (float)k0; o[1] = (float)(k1 - k0); o[2] = 1.0f / fmaxf(wsum, 1e-8f);
  #pragma unroll
  for (int j = 0; j < 5; ++j) o[3 + j] = (j < k1 - k0) ? wn[j] : 0.f;
}

#define LDSWAIT asm volatile("s_waitcnt lgkmcnt(0)" ::: "memory")

__device__ __forceinline__ void init6(f4* acc, const float* s, int off) {
  #pragma unroll
  for (int mt = 0; mt < 6; ++mt) {
    const float4 bb = *reinterpret_cast<const float4*>(s + mt * 16 + off);
    acc[mt] = (f4){bb.x, bb.y, bb.z, bb.w};
  }
}
__device__ __forceinline__ f4 init1(const float* s, int mt, int off) {
  const float4 bb = *reinterpret_cast<const float4*>(s + mt * 16 + off);
  return (f4){bb.x, bb.y, bb.z, bb.w};
}
__device__ __forceinline__ void ln96(const f4* acc, float& mean, float& rs) {
  float sm = 0.f, sq = 0.f;
  #pragma unroll
  for (int mt = 0; mt < 6; ++mt)
    #pragma unroll
    for (int r = 0; r < 4; ++r) { const float v = acc[mt][r]; sm += v; sq = fmaf(v, v, sq); }
  sm += __shfl_xor(sm, 16); sm += __shfl_xor(sm, 32);
  sq += __shfl_xor(sq, 16); sq += __shfl_xor(sq, 32);
  mean = sm * (1.f / 96.f);
  rs = rsqrtf(sq * (1.f / 96.f) - mean * mean + 1e-5f);
}
__device__ __forceinline__ void load6s(bh8* dst, const unsigned short* p, int step9) {
  #pragma unroll
  for (int mt = 0; mt < 6; ++mt)
    dst[mt] = *reinterpret_cast<const bh8*>(p + ((mt * step9) << 9));
}

// ---- fused MFMA kernel; per-mt QKVO tail for low reg pressure; 4 blocks/CU ----
__global__ __launch_bounds__(256, 4) void fused_mfma(
    const float* __restrict__ mix, const float* __restrict__ spin,
    const unsigned short* __restrict__ enc16, const float* __restrict__ enc_b, const float* __restrict__ enc_a,
    const unsigned short* __restrict__ dec16, const float* __restrict__ dec_b, const float* __restrict__ dec_a,
    const float* __restrict__ gb, const float* __restrict__ ftab,
    const unsigned short* __restrict__ q16, const float* __restrict__ qb,
    const unsigned short* __restrict__ k16, const float* __restrict__ kb,
    const unsigned short* __restrict__ v16, const float* __restrict__ vb,
    const unsigned short* __restrict__ o16, const float* __restrict__ ob,
    float* __restrict__ out) {
  const int id0 = (int)blockIdx.x;
  const int id  = (id0 & 7) * 2056 + (id0 >> 3);   // bijective XCD swizzle (16448 = 8*2056)
  const int tt  = id & 15;
  const int fb  = id >> 4;
  const int f   = fb % 257;
  const int b   = fb / 257;
  const int t0  = tt << 6;

  const int tid  = threadIdx.x;
  const int lane = tid & 63;
  const int w    = tid >> 6;
  const int g    = lane >> 4;
  const int n    = lane & 15;
  const int col  = (w << 4) + n;
  const int t    = t0 + col;
  const bool tv  = t < 1000;
  const int tcl  = tv ? t : 999;
  const int sw   = (n & 7) << 3;
  const int lb   = lane << 3;

  __shared__ __align__(16) unsigned short XT[64 * 128];
  __shared__ __align__(16) float stage[5 * 512 + 384];
  unsigned short* xw = XT + col * 128;

  const float* ft = ftab + f * 8;
  const int k0 = (int)ft[0];
  const int nb = (int)ft[1];
  const float winv = ft[2];

  // cooperative stage: per band (stride 512): encB96|decB96|gb192|ea,da,win ; tail: qb|kb|vb|ob
  {
    const int tot = (nb << 9) + 384;
    for (int i = tid; i < tot; i += 256) {
      const int kk = i >> 9, r = i & 511;
      float v = 0.f;
      if (kk < nb) {
        const int k = k0 + kk;
        if      (r < 96)  v = enc_b[k * 96 + r];
        else if (r < 192) v = dec_b[k * 96 + (r - 96)];
        else if (r < 384) v = gb[(k * 4 + b) * 192 + (r - 192)];
        else if (r == 384) v = enc_a[k];
        else if (r == 385) v = dec_a[k];
        else if (r == 386) v = ft[3 + kk];
      } else {
        const int r2 = i - (nb << 9);
        v = (r2 < 96) ? qb[r2] : (r2 < 192) ? kb[r2 - 96] : (r2 < 288) ? vb[r2 - 192] : ob[r2 - 288];
      }
      stage[i] = v;
    }
  }

  const float* spL = spin + b * 64 * FT + f * 1000 + tcl;
  const float* mxL = mix  + b * 96 * FT + f * 1000 + tcl;

  // spin prefetch (read-once)
  bh8 spb[2];
  {
    float spf[16];
    #pragma unroll
    for (int j = 0; j < 8; ++j) spf[j]     = __builtin_nontemporal_load(spL + (g * 8 + j) * FT);
    #pragma unroll
    for (int j = 0; j < 8; ++j) spf[8 + j] = __builtin_nontemporal_load(spL + (32 + g * 8 + j) * FT);
    #pragma unroll
    for (int kt = 0; kt < 2; ++kt)
      #pragma unroll
      for (int j = 0; j < 8; ++j) spb[kt][j] = (short)b16u(spf[kt * 8 + j]);
  }

  // rotating prefetch buffer: enc g0 of first band
  bh8 pre[6];
  load6s(pre, enc16 + k0 * 6144 + lb, 2);

  __syncthreads();   // stage visible

  f4 macc[6];
  #pragma unroll
  for (int mt = 0; mt < 6; ++mt) macc[mt] = (f4){0.f, 0.f, 0.f, 0.f};

  const int oo = g * 4;

  // ---------------- band loop; INV: pre = enc g0(k) at entry ----------------
  for (int kk = 0; kk < nb; ++kk) {
    const int k = k0 + kk;
    const unsigned short* ew  = enc16 + k * 6144 + lb;
    const unsigned short* dwp = dec16 + k * 9216 + lb;
    const float* stg = stage + (kk << 9);

    // ---- enc: 96x64; kt=0 from pre, kt=1 inline ----
    f4 acc[6];
    init6(acc, stg, oo);
    #pragma unroll
    for (int mt = 0; mt < 6; ++mt)
      acc[mt] = __builtin_amdgcn_mfma_f32_16x16x32_bf16(pre[mt], spb[0], acc[mt], 0, 0, 0);
    #pragma unroll
    for (int mt = 0; mt < 6; ++mt) {
      const bh8 af = *reinterpret_cast<const bh8*>(ew + ((mt * 2 + 1) << 9));
      acc[mt] = __builtin_amdgcn_mfma_f32_16x16x32_bf16(af, spb[1], acc[mt], 0, 0, 0);
    }

    // pre dead -> refill with dec g0 (hides under LN1/FiLM)
    load6s(pre, dwp, 3);

    float mean, rs;
    ln96(acc, mean, rs);
    const float ea = stg[384];
    #pragma unroll
    for (int mt = 0; mt < 6; ++mt) {
      const float4 ga = *reinterpret_cast<const float4*>(stg + 192 + mt * 16 + oo);
      const float4 be = *reinterpret_cast<const float4*>(stg + 288 + mt * 16 + oo);
      float x0 = (acc[mt][0] - mean) * rs; x0 = (x0 >= 0.f) ? x0 : ea * x0;
      float x1 = (acc[mt][1] - mean) * rs; x1 = (x1 >= 0.f) ? x1 : ea * x1;
      float x2 = (acc[mt][2] - mean) * rs; x2 = (x2 >= 0.f) ? x2 : ea * x2;
      float x3 = (acc[mt][3] - mean) * rs; x3 = (x3 >= 0.f) ? x3 : ea * x3;
      uint2 u;
      u.x = pk2(fmaf(ga.x, x0, be.x), fmaf(ga.y, x1, be.y));
      u.y = pk2(fmaf(ga.z, x2, be.z), fmaf(ga.w, x3, be.w));
      *reinterpret_cast<uint2*>(xw + ((mt * 16 + g * 4) ^ sw)) = u;
    }
    LDSWAIT;

    // ---- dec: 96x96 from XT; kt=0 from pre ----
    f4 dacc[6];
    init6(dacc, stg + 96, oo);
    {
      const bh8 bf0 = *reinterpret_cast<const bh8*>(xw + ((0 * 32 + g * 8) ^ sw));
      #pragma unroll
      for (int mt = 0; mt < 6; ++mt)
        dacc[mt] = __builtin_amdgcn_mfma_f32_16x16x32_bf16(pre[mt], bf0, dacc[mt], 0, 0, 0);
    }

    // pre dead -> refill with next band's enc g0 (or Q g0)
    {
      const bool more = (kk + 1 < nb);
      load6s(pre, more ? (enc16 + (k + 1) * 6144 + lb) : (q16 + lb), more ? 2 : 3);
    }

    #pragma unroll
    for (int kt = 1; kt < 3; ++kt) {
      const bh8 bf = *reinterpret_cast<const bh8*>(xw + ((kt * 32 + g * 8) ^ sw));
      #pragma unroll
      for (int mt = 0; mt < 6; ++mt) {
        const bh8 af = *reinterpret_cast<const bh8*>(dwp + ((mt * 3 + kt) << 9));
        dacc[mt] = __builtin_amdgcn_mfma_f32_16x16x32_bf16(af, bf, dacc[mt], 0, 0, 0);
      }
    }
    float mean2, rs2;
    ln96(dacc, mean2, rs2);
    const float da = stg[385];
    const float win = stg[386];
    #pragma unroll
    for (int mt = 0; mt < 6; ++mt)
      #pragma unroll
      for (int r = 0; r < 4; ++r) {
        float x = (dacc[mt][r] - mean2) * rs2;
        x = (x >= 0.f) ? x : da * x;
        macc[mt][r] = fmaf(win, x, macc[mt][r]);
      }
  }

  // ---- mix loads (cached; residual re-read hits L1/L2) ----
  bh8 mxb[3];
  {
    float mxf[24];
    #pragma unroll
    for (int kt = 0; kt < 3; ++kt)
      #pragma unroll
      for (int j = 0; j < 8; ++j) mxf[kt * 8 + j] = mxL[(kt * 32 + g * 8 + j) * FT];
    #pragma unroll
    for (int kt = 0; kt < 3; ++kt)
      #pragma unroll
      for (int j = 0; j < 8; ++j) mxb[kt][j] = (short)b16u(mxf[kt * 8 + j]);
  }

  // ---- merged -> XT ----
  #pragma unroll
  for (int mt = 0; mt < 6; ++mt) {
    uint2 u;
    u.x = pk2(macc[mt][0] * winv, macc[mt][1] * winv);
    u.y = pk2(macc[mt][2] * winv, macc[mt][3] * winv);
    *reinterpret_cast<uint2*>(xw + ((mt * 16 + g * 4) ^ sw)) = u;
  }
  LDSWAIT;
  bh8 gfr[3];
  #pragma unroll
  for (int kt = 0; kt < 3; ++kt) gfr[kt] = *reinterpret_cast<const bh8*>(xw + ((kt * 32 + g * 8) ^ sw));

  const float* stQ = stage + (nb << 9);
  const unsigned short* qp16 = q16 + lb;
  const unsigned short* kp16 = k16 + lb;
  const unsigned short* vp16 = v16 + lb;
  const unsigned short* op16 = o16 + lb;

  // ---- Q,K per-mt (low reg pressure): p = sum qa.ka ----
  float p = 0.f;
  #pragma unroll
  for (int mt = 0; mt < 6; ++mt) {
    f4 qa = init1(stQ, mt, oo);
    qa = __builtin_amdgcn_mfma_f32_16x16x32_bf16(pre[mt], mxb[0], qa, 0, 0, 0);
    #pragma unroll
    for (int kt = 1; kt < 3; ++kt) {
      const bh8 af = *reinterpret_cast<const bh8*>(qp16 + ((mt * 3 + kt) << 9));
      qa = __builtin_amdgcn_mfma_f32_16x16x32_bf16(af, mxb[kt], qa, 0, 0, 0);
    }
    f4 ka = init1(stQ + 96, mt, oo);
    #pragma unroll
    for (int kt = 0; kt < 3; ++kt) {
      const bh8 af = *reinterpret_cast<const bh8*>(kp16 + ((mt * 3 + kt) << 9));
      ka = __builtin_amdgcn_mfma_f32_16x16x32_bf16(af, gfr[kt], ka, 0, 0, 0);
    }
    #pragma unroll
    for (int r = 0; r < 4; ++r) p = fmaf(qa[r], ka[r], p);
  }
  p += __shfl_xor(p, 16); p += __shfl_xor(p, 32);
  const float sig = 1.f / (1.f + __expf(-p * 0.10206207261596575f));

  // ---- V per-mt, attended -> XT ----
  #pragma unroll
  for (int mt = 0; mt < 6; ++mt) {
    f4 va = init1(stQ + 192, mt, oo);
    #pragma unroll
    for (int kt = 0; kt < 3; ++kt) {
      const bh8 af = *reinterpret_cast<const bh8*>(vp16 + ((mt * 3 + kt) << 9));
      va = __builtin_amdgcn_mfma_f32_16x16x32_bf16(af, gfr[kt], va, 0, 0, 0);
    }
    uint2 u;
    u.x = pk2(va[0] * sig, va[1] * sig);
    u.y = pk2(va[2] * sig, va[3] * sig);
    *reinterpret_cast<uint2*>(xw + ((mt * 16 + g * 4) ^ sw)) = u;
  }
  // residual loads issue before the wait
  float mres[6][4];
  #pragma unroll
  for (int mt = 0; mt < 6; ++mt)
    #pragma unroll
    for (int r = 0; r < 4; ++r) mres[mt][r] = mxL[(mt * 16 + g * 4 + r) * FT];
  LDSWAIT;
  bh8 afr[3];
  #pragma unroll
  for (int kt = 0; kt < 3; ++kt) afr[kt] = *reinterpret_cast<const bh8*>(xw + ((kt * 32 + g * 8) ^ sw));

  // ---- O per-mt + residual ----
  #pragma unroll
  for (int mt = 0; mt < 6; ++mt) {
    f4 oa = init1(stQ + 288, mt, oo);
    #pragma unroll
    for (int kt = 0; kt < 3; ++kt) {
      const bh8 af = *reinterpret_cast<const bh8*>(op16 + ((mt * 3 + kt) << 9));
      oa = __builtin_amdgcn_mfma_f32_16x16x32_bf16(af, afr[kt], oa, 0, 0, 0);
    }
    if (tv) {
      const int base = (b * 96 + mt * 16 + g * 4) * FT + f * 1000 + t;
      #pragma unroll
      for (int r = 0; r < 4; ++r)
        __builtin_nontemporal_store(mres[mt][r] + oa[r], out + base + r * FT);
    }
  }
}

extern "C" void kernel_launch(void* const* d_in, const int* in_sizes, int n_in,
                              void* d_out, int out_size, void* d_ws, size_t ws_size,
                              hipStream_t stream) {
  (void)in_sizes; (void)n_in; (void)out_size; (void)ws_size;
  const float* mix   = (const float*)d_in[0];
  const float* spin  = (const float*)d_in[1];
  const float* doa   = (const float*)d_in[2];
  const float* enc_w = (const float*)d_in[3];
  const float* enc_b = (const float*)d_in[4];
  const float* enc_a = (const float*)d_in[5];
  const float* dqg_w = (const float*)d_in[6];
  const float* dqg_b = (const float*)d_in[7];
  const float* dec_w = (const float*)d_in[8];
  const float* dec_b = (const float*)d_in[9];
  const float* dec_a = (const float*)d_in[10];
  const float* qw    = (const float*)d_in[11];
  const float* qb    = (const float*)d_in[12];
  const float* kw    = (const float*)d_in[13];
  const float* kb    = (const float*)d_in[14];
  const float* vw    = (const float*)d_in[15];
  const float* vb    = (const float*)d_in[16];
  const float* oww   = (const float*)d_in[17];
  const float* obb   = (const float*)d_in[18];
  float* outp = (float*)d_out;

  unsigned short* w16 = (unsigned short*)d_ws;
  unsigned short* enc16 = w16;                 // 31*6144
  unsigned short* dec16 = w16 + 190464;        // 31*9216
  unsigned short* q16   = w16 + 476160;
  unsigned short* k16   = q16 + 9216;
  unsigned short* v16   = k16 + 9216;
  unsigned short* o16   = v16 + 9216;
  float* gbws = (float*)((char*)d_ws + 1026048);  // 31*4*192 f32 (95232 B)
  float* ftab = (float*)((char*)d_ws + 1121280);  // 257*8 f32 (8224 B)

  hipLaunchKernelGGL(prep_w, dim3(512), dim3(256), 0, stream,
                     enc_w, dec_w, qw, kw, vw, oww, w16);
  hipLaunchKernelGGL(qp_kernel, dim3(NBANDS, 4), dim3(192), 0, stream,
                     doa, dqg_w, dqg_b, gbws);
  hipLaunchKernelGGL(tab_kernel, dim3(1), dim3(320), 0, stream, ftab);
  hipLaunchKernelGGL(fused_mfma, dim3(16448), dim3(256), 0, stream,
                     mix, spin, enc16, enc_b, enc_a, dec16, dec_b, dec_a, gbws, ftab,
                     q16, qb, k16, kb, v16, vb, o16, obb, outp);
}

// Round 11
// 621.340 us; speedup vs baseline: 1.0813x; 1.0813x over previous
//
#include <hip/hip_runtime.h>
#include <math.h>

#define NBANDS 31
#define FT 257000

typedef __attribute__((ext_vector_type(8))) short bh8;
typedef __attribute__((ext_vector_type(4))) float f4;

__constant__ int d_bs[NBANDS] = {0,1,1,2,2,2,3,3,4,5,6,7,8,10,11,13,16,19,23,27,32,38,45,54,64,76,91,108,128,152,181};
__constant__ int d_be[NBANDS] = {2,3,3,3,4,4,5,6,7,8,9,11,12,14,17,20,24,28,33,39,46,55,65,77,92,109,129,153,182,216,257};

__device__ __forceinline__ unsigned short b16u(float v) {
  __bf16 h = (__bf16)v;
  return __builtin_bit_cast(unsigned short, h);
}
__device__ __forceinline__ unsigned pk2(float a, float b) {
  return (unsigned)b16u(a) | ((unsigned)b16u(b) << 16);
}
__device__ __forceinline__ float hann1(int i, int L) {
  return 0.5f - 0.5f * cosf(6.283185307179586f * (float)i / (float)L);
}
// unpack 4 bf16 (8B aligned) -> f4
__device__ __forceinline__ f4 bf4(const unsigned short* p) {
  const uint2 u = *reinterpret_cast<const uint2*>(p);
  f4 r;
  r[0] = __builtin_bit_cast(float, u.x << 16);
  r[1] = __builtin_bit_cast(float, u.x & 0xffff0000u);
  r[2] = __builtin_bit_cast(float, u.y << 16);
  r[3] = __builtin_bit_cast(float, u.y & 0xffff0000u);
  return r;
}

// ---- weight f32 -> bf16 prep, permuted into MFMA-fragment order ----
__global__ __launch_bounds__(256) void prep_w(
    const float* __restrict__ enc_w, const float* __restrict__ dec_w,
    const float* __restrict__ qw, const float* __restrict__ kw,
    const float* __restrict__ vw, const float* __restrict__ ow,
    unsigned short* __restrict__ w16) {
  const int stride = gridDim.x * blockDim.x;
  for (int i = blockIdx.x * blockDim.x + threadIdx.x; i < 513024; i += stride) {
    float v;
    if (i < 190464) {                      // enc: K=64, KT=2
      const int k = i / 6144, r = i - k * 6144;
      const int tile = r >> 9, li = r & 511;
      const int lane = li >> 3, j = li & 7;
      const int g = lane >> 4, n = lane & 15;
      const int mt = tile >> 1, kt = tile & 1;
      v = enc_w[k * 6144 + (mt * 16 + n) * 64 + kt * 32 + g * 8 + j];
    } else if (i < 476160) {               // dec: K=96, KT=3
      const int i2 = i - 190464;
      const int k = i2 / 9216, r = i2 - k * 9216;
      const int tile = r >> 9, li = r & 511;
      const int lane = li >> 3, j = li & 7;
      const int g = lane >> 4, n = lane & 15;
      const int mt = tile / 3, kt = tile - mt * 3;
      v = dec_w[k * 9216 + (mt * 16 + n) * 96 + kt * 32 + g * 8 + j];
    } else {                               // q,k,v,o
      const int i2 = i - 476160;
      const int a = i2 / 9216, r = i2 - a * 9216;
      const int tile = r >> 9, li = r & 511;
      const int lane = li >> 3, j = li & 7;
      const int g = lane >> 4, n = lane & 15;
      const int mt = tile / 3, kt = tile - mt * 3;
      const float* src = (a == 0) ? qw : (a == 1) ? kw : (a == 2) ? vw : ow;
      v = src[(mt * 16 + n) * 96 + kt * 32 + g * 8 + j];
    }
    w16[i] = b16u(v);
  }
}

__global__ __launch_bounds__(192) void qp_kernel(const float* __restrict__ doa,
                                                 const float* __restrict__ dqg_w,
                                                 const float* __restrict__ dqg_b,
                                                 float* __restrict__ gbuf) {
  const int k = blockIdx.x, b = blockIdx.y;
  const int tid = threadIdx.x;
  __shared__ float sdoa[36];
  if (tid < 36) sdoa[tid] = doa[b * 36 + tid];
  __syncthreads();
  const float* wr = dqg_w + (k * 192 + tid) * 36;
  float acc = dqg_b[k * 192 + tid];
  #pragma unroll
  for (int i = 0; i < 36; ++i) acc = fmaf(wr[i], sdoa[i], acc);
  if (tid < 96) acc += 1.0f;
  gbuf[(k * 4 + b) * 192 + tid] = acc;
}

// ---- per-f table: {k0, nb, winv, win0..win4} ----
__global__ __launch_bounds__(320) void tab_kernel(float* __restrict__ ftab) {
  const int f = blockIdx.x * blockDim.x + threadIdx.x;
  if (f >= 257) return;
  int k0 = 0; while (d_be[k0] <= f) ++k0;
  int k1 = k0; while (k1 < NBANDS && d_bs[k1] <= f) ++k1;
  float wsum = 0.f, wn[5];
  for (int k = k0; k < k1; ++k) {
    const float wv = hann1(f - d_bs[k], d_be[k] - d_bs[k]);
    wn[k - k0] = wv; wsum += wv;
  }
  float* o = ftab + f * 8;
  o[0] = (float)k0; o[1] = (float)(k1 - k0); o[2] = 1.0f / fmaxf(wsum, 1e-8f);
  #pragma unroll
  for (int j = 0; j < 5; ++j) o[3 + j] = (j < k1 - k0) ? wn[j] : 0.f;
}

#define LDSWAIT asm volatile("s_waitcnt lgkmcnt(0)" ::: "memory")

__device__ __forceinline__ void ln96(const f4* acc, float& mean, float& rs) {
  float sm = 0.f, sq = 0.f;
  #pragma unroll
  for (int mt = 0; mt < 6; ++mt)
    #pragma unroll
    for (int r = 0; r < 4; ++r) { const float v = acc[mt][r]; sm += v; sq = fmaf(v, v, sq); }
  sm += __shfl_xor(sm, 16); sm += __shfl_xor(sm, 32);
  sq += __shfl_xor(sq, 16); sq += __shfl_xor(sq, 32);
  mean = sm * (1.f / 96.f);
  rs = rsqrtf(sq * (1.f / 96.f) - mean * mean + 1e-5f);
}
__device__ __forceinline__ void load6s(bh8* dst, const unsigned short* p, int step9) {
  #pragma unroll
  for (int mt = 0; mt < 6; ++mt)
    dst[mt] = *reinterpret_cast<const bh8*>(p + ((mt * step9) << 9));
}

// ---- fused MFMA kernel; macc/mres in LDS; 4 blocks/CU target ----
__global__ __launch_bounds__(256, 4) void fused_mfma(
    const float* __restrict__ mix, const float* __restrict__ spin,
    const unsigned short* __restrict__ enc16, const float* __restrict__ enc_b, const float* __restrict__ enc_a,
    const unsigned short* __restrict__ dec16, const float* __restrict__ dec_b, const float* __restrict__ dec_a,
    const float* __restrict__ gb, const float* __restrict__ ftab,
    const unsigned short* __restrict__ q16, const float* __restrict__ qb,
    const unsigned short* __restrict__ k16, const float* __restrict__ kb,
    const unsigned short* __restrict__ v16, const float* __restrict__ vb,
    const unsigned short* __restrict__ o16, const float* __restrict__ ob,
    float* __restrict__ out) {
  const int id0 = (int)blockIdx.x;
  const int id  = (id0 & 7) * 2056 + (id0 >> 3);   // bijective XCD swizzle (16448 = 8*2056)
  const int tt  = id & 15;
  const int fb  = id >> 4;
  const int f   = fb % 257;
  const int b   = fb / 257;
  const int t0  = tt << 6;

  const int tid  = threadIdx.x;
  const int lane = tid & 63;
  const int w    = tid >> 6;
  const int g    = lane >> 4;
  const int n    = lane & 15;
  const int col  = (w << 4) + n;
  const int t    = t0 + col;
  const bool tv  = t < 1000;
  const int tcl  = tv ? t : 999;
  const int sw   = (n & 7) << 3;
  const int lb   = lane << 3;

  __shared__ __align__(16) unsigned short XT[64 * 128];
  __shared__ __align__(16) unsigned short MG[64 * 128];
  __shared__ __align__(16) unsigned short stgb[5 * 512 + 384];
  __shared__ float sband[5 * 4];
  unsigned short* xw = XT + col * 128;
  unsigned short* mg = MG + col * 128;

  const float* ft = ftab + f * 8;
  const int k0 = (int)ft[0];
  const int nb = (int)ft[1];
  const float winv = ft[2];

  // cooperative stage (bf16): per band (512): encB96|decB96|gamma96|beta96 ; tail: qb|kb|vb|ob
  {
    const int tot = (nb << 9) + 384;
    for (int i = tid; i < tot; i += 256) {
      const int kk = i >> 9, r = i & 511;
      float v = 0.f;
      if (kk < nb) {
        const int k = k0 + kk;
        if      (r < 96)  v = enc_b[k * 96 + r];
        else if (r < 192) v = dec_b[k * 96 + (r - 96)];
        else if (r < 384) v = gb[(k * 4 + b) * 192 + (r - 192)];
      } else {
        const int r2 = i - (nb << 9);
        v = (r2 < 96) ? qb[r2] : (r2 < 192) ? kb[r2 - 96] : (r2 < 288) ? vb[r2 - 192] : ob[r2 - 288];
      }
      stgb[i] = b16u(v);
    }
    if (tid < nb * 4) {
      const int kk = tid >> 2, j = tid & 3;
      sband[tid] = (j == 0) ? enc_a[k0 + kk] : (j == 1) ? dec_a[k0 + kk]
                 : (j == 2) ? ft[3 + kk] : 0.f;
    }
  }

  const float* spL = spin + b * 64 * FT + f * 1000 + tcl;
  const float* mxL = mix  + b * 96 * FT + f * 1000 + tcl;

  // spin prefetch (read-once)
  bh8 spb[2];
  {
    float spf[16];
    #pragma unroll
    for (int j = 0; j < 8; ++j) spf[j]     = __builtin_nontemporal_load(spL + (g * 8 + j) * FT);
    #pragma unroll
    for (int j = 0; j < 8; ++j) spf[8 + j] = __builtin_nontemporal_load(spL + (32 + g * 8 + j) * FT);
    #pragma unroll
    for (int kt = 0; kt < 2; ++kt)
      #pragma unroll
      for (int j = 0; j < 8; ++j) spb[kt][j] = (short)b16u(spf[kt * 8 + j]);
  }

  // rotating prefetch buffer: enc g0 of first band
  bh8 pre[6];
  load6s(pre, enc16 + k0 * 6144 + lb, 2);

  __syncthreads();   // stage visible

  const int oo = g * 4;

  // ---------------- band loop; INV: pre = enc g0(k) at entry ----------------
  for (int kk = 0; kk < nb; ++kk) {
    const int k = k0 + kk;
    const unsigned short* ew  = enc16 + k * 6144 + lb;
    const unsigned short* dwp = dec16 + k * 9216 + lb;
    const unsigned short* stg = stgb + (kk << 9);

    // ---- enc: 96x64; kt=0 from pre, kt=1 inline ----
    f4 acc[6];
    #pragma unroll
    for (int mt = 0; mt < 6; ++mt) acc[mt] = bf4(stg + mt * 16 + oo);
    #pragma unroll
    for (int mt = 0; mt < 6; ++mt)
      acc[mt] = __builtin_amdgcn_mfma_f32_16x16x32_bf16(pre[mt], spb[0], acc[mt], 0, 0, 0);
    #pragma unroll
    for (int mt = 0; mt < 6; ++mt) {
      const bh8 af = *reinterpret_cast<const bh8*>(ew + ((mt * 2 + 1) << 9));
      acc[mt] = __builtin_amdgcn_mfma_f32_16x16x32_bf16(af, spb[1], acc[mt], 0, 0, 0);
    }

    // pre dead -> refill with dec g0 (hides under LN1/FiLM)
    load6s(pre, dwp, 3);

    float mean, rs;
    ln96(acc, mean, rs);
    const float ea = sband[kk * 4];
    #pragma unroll
    for (int mt = 0; mt < 6; ++mt) {
      const f4 ga = bf4(stg + 192 + mt * 16 + oo);
      const f4 be = bf4(stg + 288 + mt * 16 + oo);
      float x0 = (acc[mt][0] - mean) * rs; x0 = (x0 >= 0.f) ? x0 : ea * x0;
      float x1 = (acc[mt][1] - mean) * rs; x1 = (x1 >= 0.f) ? x1 : ea * x1;
      float x2 = (acc[mt][2] - mean) * rs; x2 = (x2 >= 0.f) ? x2 : ea * x2;
      float x3 = (acc[mt][3] - mean) * rs; x3 = (x3 >= 0.f) ? x3 : ea * x3;
      uint2 u;
      u.x = pk2(fmaf(ga[0], x0, be[0]), fmaf(ga[1], x1, be[1]));
      u.y = pk2(fmaf(ga[2], x2, be[2]), fmaf(ga[3], x3, be[3]));
      *reinterpret_cast<uint2*>(xw + ((mt * 16 + oo) ^ sw)) = u;
    }
    LDSWAIT;

    // ---- dec: 96x96 from XT; kt=0 from pre ----
    f4 dacc[6];
    #pragma unroll
    for (int mt = 0; mt < 6; ++mt) dacc[mt] = bf4(stg + 96 + mt * 16 + oo);
    {
      const bh8 bf0 = *reinterpret_cast<const bh8*>(xw + ((0 * 32 + g * 8) ^ sw));
      #pragma unroll
      for (int mt = 0; mt < 6; ++mt)
        dacc[mt] = __builtin_amdgcn_mfma_f32_16x16x32_bf16(pre[mt], bf0, dacc[mt], 0, 0, 0);
    }

    // pre dead -> refill with next band's enc g0 (or Q g0)
    {
      const bool more = (kk + 1 < nb);
      load6s(pre, more ? (enc16 + (k + 1) * 6144 + lb) : (q16 + lb), more ? 2 : 3);
    }

    #pragma unroll
    for (int kt = 1; kt < 3; ++kt) {
      const bh8 bf = *reinterpret_cast<const bh8*>(xw + ((kt * 32 + g * 8) ^ sw));
      #pragma unroll
      for (int mt = 0; mt < 6; ++mt) {
        const bh8 af = *reinterpret_cast<const bh8*>(dwp + ((mt * 3 + kt) << 9));
        dacc[mt] = __builtin_amdgcn_mfma_f32_16x16x32_bf16(af, bf, dacc[mt], 0, 0, 0);
      }
    }
    float mean2, rs2;
    ln96(dacc, mean2, rs2);
    const float da  = sband[kk * 4 + 1];
    const float win = sband[kk * 4 + 2];
    // merged accumulate in LDS (bf16 RMW; first band writes directly)
    #pragma unroll
    for (int mt = 0; mt < 6; ++mt) {
      float x0 = (dacc[mt][0] - mean2) * rs2; x0 = (x0 >= 0.f) ? x0 : da * x0;
      float x1 = (dacc[mt][1] - mean2) * rs2; x1 = (x1 >= 0.f) ? x1 : da * x1;
      float x2 = (dacc[mt][2] - mean2) * rs2; x2 = (x2 >= 0.f) ? x2 : da * x2;
      float x3 = (dacc[mt][3] - mean2) * rs2; x3 = (x3 >= 0.f) ? x3 : da * x3;
      unsigned short* mp = mg + ((mt * 16 + oo) ^ sw);
      uint2 u;
      if (kk == 0) {
        u.x = pk2(win * x0, win * x1);
        u.y = pk2(win * x2, win * x3);
      } else {
        const f4 cur = bf4(mp);
        u.x = pk2(fmaf(win, x0, cur[0]), fmaf(win, x1, cur[1]));
        u.y = pk2(fmaf(win, x2, cur[2]), fmaf(win, x3, cur[3]));
      }
      *reinterpret_cast<uint2*>(mp) = u;
    }
  }

  // ---- mix loads (single pass) -> B fragments ----
  bh8 mxb[3];
  {
    float mxf[24];
    #pragma unroll
    for (int kt = 0; kt < 3; ++kt)
      #pragma unroll
      for (int j = 0; j < 8; ++j) mxf[kt * 8 + j] = __builtin_nontemporal_load(mxL + (kt * 32 + g * 8 + j) * FT);
    #pragma unroll
    for (int kt = 0; kt < 3; ++kt)
      #pragma unroll
      for (int j = 0; j < 8; ++j) mxb[kt][j] = (short)b16u(mxf[kt * 8 + j]);
  }

  // ---- merged finalize: MG -> XT (scaled by winv) ----
  #pragma unroll
  for (int mt = 0; mt < 6; ++mt) {
    const f4 mv = bf4(mg + ((mt * 16 + oo) ^ sw));
    uint2 u;
    u.x = pk2(mv[0] * winv, mv[1] * winv);
    u.y = pk2(mv[2] * winv, mv[3] * winv);
    *reinterpret_cast<uint2*>(xw + ((mt * 16 + oo) ^ sw)) = u;
  }
  LDSWAIT;
  bh8 gfr[3];
  #pragma unroll
  for (int kt = 0; kt < 3; ++kt) gfr[kt] = *reinterpret_cast<const bh8*>(xw + ((kt * 32 + g * 8) ^ sw));

  // park mix bf16 in MG (free now) for the residual read at O-phase
  #pragma unroll
  for (int kt = 0; kt < 3; ++kt)
    *reinterpret_cast<bh8*>(mg + ((kt * 32 + g * 8) ^ sw)) = mxb[kt];

  const unsigned short* stQ = stgb + (nb << 9);
  const unsigned short* qp16 = q16 + lb;
  const unsigned short* kp16 = k16 + lb;
  const unsigned short* vp16 = v16 + lb;
  const unsigned short* op16 = o16 + lb;

  // ---- Q,K per-mt: p = sum qa.ka ----
  float p = 0.f;
  #pragma unroll
  for (int mt = 0; mt < 6; ++mt) {
    f4 qa = bf4(stQ + mt * 16 + oo);
    qa = __builtin_amdgcn_mfma_f32_16x16x32_bf16(pre[mt], mxb[0], qa, 0, 0, 0);
    #pragma unroll
    for (int kt = 1; kt < 3; ++kt) {
      const bh8 af = *reinterpret_cast<const bh8*>(qp16 + ((mt * 3 + kt) << 9));
      qa = __builtin_amdgcn_mfma_f32_16x16x32_bf16(af, mxb[kt], qa, 0, 0, 0);
    }
    f4 ka = bf4(stQ + 96 + mt * 16 + oo);
    #pragma unroll
    for (int kt = 0; kt < 3; ++kt) {
      const bh8 af = *reinterpret_cast<const bh8*>(kp16 + ((mt * 3 + kt) << 9));
      ka = __builtin_amdgcn_mfma_f32_16x16x32_bf16(af, gfr[kt], ka, 0, 0, 0);
    }
    #pragma unroll
    for (int r = 0; r < 4; ++r) p = fmaf(qa[r], ka[r], p);
  }
  p += __shfl_xor(p, 16); p += __shfl_xor(p, 32);
  const float sig = 1.f / (1.f + __expf(-p * 0.10206207261596575f));

  // ---- V per-mt, attended -> XT ----
  #pragma unroll
  for (int mt = 0; mt < 6; ++mt) {
    f4 va = bf4(stQ + 192 + mt * 16 + oo);
    #pragma unroll
    for (int kt = 0; kt < 3; ++kt) {
      const bh8 af = *reinterpret_cast<const bh8*>(vp16 + ((mt * 3 + kt) << 9));
      va = __builtin_amdgcn_mfma_f32_16x16x32_bf16(af, gfr[kt], va, 0, 0, 0);
    }
    uint2 u;
    u.x = pk2(va[0] * sig, va[1] * sig);
    u.y = pk2(va[2] * sig, va[3] * sig);
    *reinterpret_cast<uint2*>(xw + ((mt * 16 + oo) ^ sw)) = u;
  }
  LDSWAIT;
  bh8 afr[3];
  #pragma unroll
  for (int kt = 0; kt < 3; ++kt) afr[kt] = *reinterpret_cast<const bh8*>(xw + ((kt * 32 + g * 8) ^ sw));

  // ---- O per-mt + residual (from MG) ----
  #pragma unroll
  for (int mt = 0; mt < 6; ++mt) {
    f4 oa = bf4(stQ + 288 + mt * 16 + oo);
    #pragma unroll
    for (int kt = 0; kt < 3; ++kt) {
      const bh8 af = *reinterpret_cast<const bh8*>(op16 + ((mt * 3 + kt) << 9));
      oa = __builtin_amdgcn_mfma_f32_16x16x32_bf16(af, afr[kt], oa, 0, 0, 0);
    }
    if (tv) {
      const f4 mr = bf4(mg + ((mt * 16 + oo) ^ sw));
      const int base = (b * 96 + mt * 16 + oo) * FT + f * 1000 + t;
      #pragma unroll
      for (int r = 0; r < 4; ++r)
        __builtin_nontemporal_store(mr[r] + oa[r], out + base + r * FT);
    }
  }
}

extern "C" void kernel_launch(void* const* d_in, const int* in_sizes, int n_in,
                              void* d_out, int out_size, void* d_ws, size_t ws_size,
                              hipStream_t stream) {
  (void)in_sizes; (void)n_in; (void)out_size; (void)ws_size;
  const float* mix   = (const float*)d_in[0];
  const float* spin  = (const float*)d_in[1];
  const float* doa   = (const float*)d_in[2];
  const float* enc_w = (const float*)d_in[3];
  const float* enc_b = (const float*)d_in[4];
  const float* enc_a = (const float*)d_in[5];
  const float* dqg_w = (const float*)d_in[6];
  const float* dqg_b = (const float*)d_in[7];
  const float* dec_w = (const float*)d_in[8];
  const float* dec_b = (const float*)d_in[9];
  const float* dec_a = (const float*)d_in[10];
  const float* qw    = (const float*)d_in[11];
  const float* qb    = (const float*)d_in[12];
  const float* kw    = (const float*)d_in[13];
  const float* kb    = (const float*)d_in[14];
  const float* vw    = (const float*)d_in[15];
  const float* vb    = (const float*)d_in[16];
  const float* oww   = (const float*)d_in[17];
  const float* obb   = (const float*)d_in[18];
  float* outp = (float*)d_out;

  unsigned short* w16 = (unsigned short*)d_ws;
  unsigned short* enc16 = w16;                 // 31*6144
  unsigned short* dec16 = w16 + 190464;        // 31*9216
  unsigned short* q16   = w16 + 476160;
  unsigned short* k16   = q16 + 9216;
  unsigned short* v16   = k16 + 9216;
  unsigned short* o16   = v16 + 9216;
  float* gbws = (float*)((char*)d_ws + 1026048);  // 31*4*192 f32 (95232 B)
  float* ftab = (float*)((char*)d_ws + 1121280);  // 257*8 f32 (8224 B)

  hipLaunchKernelGGL(prep_w, dim3(512), dim3(256), 0, stream,
                     enc_w, dec_w, qw, kw, vw, oww, w16);
  hipLaunchKernelGGL(qp_kernel, dim3(NBANDS, 4), dim3(192), 0, stream,
                     doa, dqg_w, dqg_b, gbws);
  hipLaunchKernelGGL(tab_kernel, dim3(1), dim3(320), 0, stream, ftab);
  hipLaunchKernelGGL(fused_mfma, dim3(16448), dim3(256), 0, stream,
                     mix, spin, enc16, enc_b, enc_a, dec16, dec_b, dec_a, gbws, ftab,
                     q16, qb, k16, kb, v16, vb, o16, obb, outp);
}

// Round 12
// 553.186 us; speedup vs baseline: 1.2145x; 1.1232x over previous
//
#include <hip/hip_runtime.h>
#include <math.h>

#define NBANDS 31
#define FT 257000

typedef __attribute__((ext_vector_type(8))) short bh8;
typedef __attribute__((ext_vector_type(4))) float f4;

__constant__ int d_bs[NBANDS] = {0,1,1,2,2,2,3,3,4,5,6,7,8,10,11,13,16,19,23,27,32,38,45,54,64,76,91,108,128,152,181};
__constant__ int d_be[NBANDS] = {2,3,3,3,4,4,5,6,7,8,9,11,12,14,17,20,24,28,33,39,46,55,65,77,92,109,129,153,182,216,257};

__device__ __forceinline__ unsigned short b16u(float v) {
  __bf16 h = (__bf16)v;
  return __builtin_bit_cast(unsigned short, h);
}
__device__ __forceinline__ unsigned pk2(float a, float b) {
  return (unsigned)b16u(a) | ((unsigned)b16u(b) << 16);
}
__device__ __forceinline__ float hann1(int i, int L) {
  return 0.5f - 0.5f * cosf(6.283185307179586f * (float)i / (float)L);
}

// ---- weight f32 -> bf16 prep, permuted into MFMA-fragment order ----
__global__ __launch_bounds__(256) void prep_w(
    const float* __restrict__ enc_w, const float* __restrict__ dec_w,
    const float* __restrict__ qw, const float* __restrict__ kw,
    const float* __restrict__ vw, const float* __restrict__ ow,
    unsigned short* __restrict__ w16) {
  const int stride = gridDim.x * blockDim.x;
  for (int i = blockIdx.x * blockDim.x + threadIdx.x; i < 513024; i += stride) {
    float v;
    if (i < 190464) {                      // enc: K=64, KT=2
      const int k = i / 6144, r = i - k * 6144;
      const int tile = r >> 9, li = r & 511;
      const int lane = li >> 3, j = li & 7;
      const int g = lane >> 4, n = lane & 15;
      const int mt = tile >> 1, kt = tile & 1;
      v = enc_w[k * 6144 + (mt * 16 + n) * 64 + kt * 32 + g * 8 + j];
    } else if (i < 476160) {               // dec: K=96, KT=3
      const int i2 = i - 190464;
      const int k = i2 / 9216, r = i2 - k * 9216;
      const int tile = r >> 9, li = r & 511;
      const int lane = li >> 3, j = li & 7;
      const int g = lane >> 4, n = lane & 15;
      const int mt = tile / 3, kt = tile - mt * 3;
      v = dec_w[k * 9216 + (mt * 16 + n) * 96 + kt * 32 + g * 8 + j];
    } else {                               // q,k,v,o
      const int i2 = i - 476160;
      const int a = i2 / 9216, r = i2 - a * 9216;
      const int tile = r >> 9, li = r & 511;
      const int lane = li >> 3, j = li & 7;
      const int g = lane >> 4, n = lane & 15;
      const int mt = tile / 3, kt = tile - mt * 3;
      const float* src = (a == 0) ? qw : (a == 1) ? kw : (a == 2) ? vw : ow;
      v = src[(mt * 16 + n) * 96 + kt * 32 + g * 8 + j];
    }
    w16[i] = b16u(v);
  }
}

__global__ __launch_bounds__(192) void qp_kernel(const float* __restrict__ doa,
                                                 const float* __restrict__ dqg_w,
                                                 const float* __restrict__ dqg_b,
                                                 float* __restrict__ gbuf) {
  const int k = blockIdx.x, b = blockIdx.y;
  const int tid = threadIdx.x;
  __shared__ float sdoa[36];
  if (tid < 36) sdoa[tid] = doa[b * 36 + tid];
  __syncthreads();
  const float* wr = dqg_w + (k * 192 + tid) * 36;
  float acc = dqg_b[k * 192 + tid];
  #pragma unroll
  for (int i = 0; i < 36; ++i) acc = fmaf(wr[i], sdoa[i], acc);
  if (tid < 96) acc += 1.0f;
  gbuf[(k * 4 + b) * 192 + tid] = acc;
}

// ---- per-f table: {k0, nb, winv, win0..win4} ----
__global__ __launch_bounds__(320) void tab_kernel(float* __restrict__ ftab) {
  const int f = blockIdx.x * blockDim.x + threadIdx.x;
  if (f >= 257) return;
  int k0 = 0; while (d_be[k0] <= f) ++k0;
  int k1 = k0; while (k1 < NBANDS && d_bs[k1] <= f) ++k1;
  float wsum = 0.f, wn[5];
  for (int k = k0; k < k1; ++k) {
    const float wv = hann1(f - d_bs[k], d_be[k] - d_bs[k]);
    wn[k - k0] = wv; wsum += wv;
  }
  float* o = ftab + f * 8;
  o[0] = (float)k0; o[1] = (float)(k1 - k0); o[2] = 1.0f / fmaxf(wsum, 1e-8f);
  #pragma unroll
  for (int j = 0; j < 5; ++j) o[3 + j] = (j < k1 - k0) ? wn[j] : 0.f;
}

#define LDSWAIT asm volatile("s_waitcnt lgkmcnt(0)" ::: "memory")

__device__ __forceinline__ void init6(f4* acc, const float* s, int off) {
  #pragma unroll
  for (int mt = 0; mt < 6; ++mt) {
    const float4 bb = *reinterpret_cast<const float4*>(s + mt * 16 + off);
    acc[mt] = (f4){bb.x, bb.y, bb.z, bb.w};
  }
}
__device__ __forceinline__ void ln96(const f4* acc, float& mean, float& rs) {
  float sm = 0.f, sq = 0.f;
  #pragma unroll
  for (int mt = 0; mt < 6; ++mt)
    #pragma unroll
    for (int r = 0; r < 4; ++r) { const float v = acc[mt][r]; sm += v; sq = fmaf(v, v, sq); }
  sm += __shfl_xor(sm, 16); sm += __shfl_xor(sm, 32);
  sq += __shfl_xor(sq, 16); sq += __shfl_xor(sq, 32);
  mean = sm * (1.f / 96.f);
  rs = rsqrtf(sq * (1.f / 96.f) - mean * mean + 1e-5f);
}
__device__ __forceinline__ void load6s(bh8* dst, const unsigned short* p, int step9) {
  #pragma unroll
  for (int mt = 0; mt < 6; ++mt)
    dst[mt] = *reinterpret_cast<const bh8*>(p + ((mt * step9) << 9));
}

// ---- fused MFMA kernel; R9 structure + LDS-staged full-line output stores ----
__global__ __launch_bounds__(256, 3) void fused_mfma(
    const float* __restrict__ mix, const float* __restrict__ spin,
    const unsigned short* __restrict__ enc16, const float* __restrict__ enc_b, const float* __restrict__ enc_a,
    const unsigned short* __restrict__ dec16, const float* __restrict__ dec_b, const float* __restrict__ dec_a,
    const float* __restrict__ gb, const float* __restrict__ ftab,
    const unsigned short* __restrict__ q16, const float* __restrict__ qb,
    const unsigned short* __restrict__ k16, const float* __restrict__ kb,
    const unsigned short* __restrict__ v16, const float* __restrict__ vb,
    const unsigned short* __restrict__ o16, const float* __restrict__ ob,
    float* __restrict__ out) {
  const int id0 = (int)blockIdx.x;
  const int id  = (id0 & 7) * 2056 + (id0 >> 3);   // bijective XCD swizzle (16448 = 8*2056)
  const int tt  = id & 15;
  const int fb  = id >> 4;
  const int f   = fb % 257;
  const int b   = fb / 257;
  const int t0  = tt << 6;

  const int tid  = threadIdx.x;
  const int lane = tid & 63;
  const int w    = tid >> 6;
  const int g    = lane >> 4;
  const int n    = lane & 15;
  const int col  = (w << 4) + n;
  const int t    = t0 + col;
  const bool tv  = t < 1000;
  const int tcl  = tv ? t : 999;
  const int sw   = (n & 7) << 3;
  const int lb   = lane << 3;

  __shared__ __align__(16) unsigned short XT[64 * 128];
  __shared__ __align__(16) float stage[5 * 512 + 384];
  __shared__ __align__(16) float OS[96 * 65];       // f32 output staging, stride 65
  unsigned short* xw = XT + col * 128;

  const float* ft = ftab + f * 8;
  const int k0 = (int)ft[0];
  const int nb = (int)ft[1];
  const float winv = ft[2];

  // cooperative stage: per band (stride 512): encB96|decB96|gb192|ea,da,win ; tail: qb|kb|vb|ob
  {
    const int tot = (nb << 9) + 384;
    for (int i = tid; i < tot; i += 256) {
      const int kk = i >> 9, r = i & 511;
      float v = 0.f;
      if (kk < nb) {
        const int k = k0 + kk;
        if      (r < 96)  v = enc_b[k * 96 + r];
        else if (r < 192) v = dec_b[k * 96 + (r - 96)];
        else if (r < 384) v = gb[(k * 4 + b) * 192 + (r - 192)];
        else if (r == 384) v = enc_a[k];
        else if (r == 385) v = dec_a[k];
        else if (r == 386) v = ft[3 + kk];
      } else {
        const int r2 = i - (nb << 9);
        v = (r2 < 96) ? qb[r2] : (r2 < 192) ? kb[r2 - 96] : (r2 < 288) ? vb[r2 - 192] : ob[r2 - 288];
      }
      stage[i] = v;
    }
  }

  const float* spL = spin + b * 64 * FT + f * 1000 + tcl;
  const float* mxL = mix  + b * 96 * FT + f * 1000 + tcl;

  // spin prefetch (read-once)
  bh8 spb[2];
  {
    float spf[16];
    #pragma unroll
    for (int j = 0; j < 8; ++j) spf[j]     = __builtin_nontemporal_load(spL + (g * 8 + j) * FT);
    #pragma unroll
    for (int j = 0; j < 8; ++j) spf[8 + j] = __builtin_nontemporal_load(spL + (32 + g * 8 + j) * FT);
    #pragma unroll
    for (int kt = 0; kt < 2; ++kt)
      #pragma unroll
      for (int j = 0; j < 8; ++j) spb[kt][j] = (short)b16u(spf[kt * 8 + j]);
  }

  // rotating prefetch buffer: enc g0 of first band
  bh8 pre[6];
  load6s(pre, enc16 + k0 * 6144 + lb, 2);

  __syncthreads();   // stage visible

  f4 macc[6];
  #pragma unroll
  for (int mt = 0; mt < 6; ++mt) macc[mt] = (f4){0.f, 0.f, 0.f, 0.f};

  const int oo = g * 4;

  // ---------------- band loop; INV: pre = enc g0(k) at entry ----------------
  for (int kk = 0; kk < nb; ++kk) {
    const int k = k0 + kk;
    const unsigned short* ew  = enc16 + k * 6144 + lb;
    const unsigned short* dwp = dec16 + k * 9216 + lb;
    const float* stg = stage + (kk << 9);

    // ---- enc: 96x64; kt=0 from pre, kt=1 inline ----
    f4 acc[6];
    init6(acc, stg, oo);
    #pragma unroll
    for (int mt = 0; mt < 6; ++mt)
      acc[mt] = __builtin_amdgcn_mfma_f32_16x16x32_bf16(pre[mt], spb[0], acc[mt], 0, 0, 0);
    #pragma unroll
    for (int mt = 0; mt < 6; ++mt) {
      const bh8 af = *reinterpret_cast<const bh8*>(ew + ((mt * 2 + 1) << 9));
      acc[mt] = __builtin_amdgcn_mfma_f32_16x16x32_bf16(af, spb[1], acc[mt], 0, 0, 0);
    }

    // pre dead -> refill with dec g0 (hides under LN1/FiLM)
    load6s(pre, dwp, 3);

    float mean, rs;
    ln96(acc, mean, rs);
    const float ea = stg[384];
    #pragma unroll
    for (int mt = 0; mt < 6; ++mt) {
      const float4 ga = *reinterpret_cast<const float4*>(stg + 192 + mt * 16 + oo);
      const float4 be = *reinterpret_cast<const float4*>(stg + 288 + mt * 16 + oo);
      float x0 = (acc[mt][0] - mean) * rs; x0 = (x0 >= 0.f) ? x0 : ea * x0;
      float x1 = (acc[mt][1] - mean) * rs; x1 = (x1 >= 0.f) ? x1 : ea * x1;
      float x2 = (acc[mt][2] - mean) * rs; x2 = (x2 >= 0.f) ? x2 : ea * x2;
      float x3 = (acc[mt][3] - mean) * rs; x3 = (x3 >= 0.f) ? x3 : ea * x3;
      uint2 u;
      u.x = pk2(fmaf(ga.x, x0, be.x), fmaf(ga.y, x1, be.y));
      u.y = pk2(fmaf(ga.z, x2, be.z), fmaf(ga.w, x3, be.w));
      *reinterpret_cast<uint2*>(xw + ((mt * 16 + g * 4) ^ sw)) = u;
    }
    LDSWAIT;

    // ---- dec: 96x96 from XT; kt=0 from pre ----
    f4 dacc[6];
    init6(dacc, stg + 96, oo);
    {
      const bh8 bf0 = *reinterpret_cast<const bh8*>(xw + ((0 * 32 + g * 8) ^ sw));
      #pragma unroll
      for (int mt = 0; mt < 6; ++mt)
        dacc[mt] = __builtin_amdgcn_mfma_f32_16x16x32_bf16(pre[mt], bf0, dacc[mt], 0, 0, 0);
    }

    // pre dead -> refill with next band's enc g0 (or Q g0)
    {
      const bool more = (kk + 1 < nb);
      load6s(pre, more ? (enc16 + (k + 1) * 6144 + lb) : (q16 + lb), more ? 2 : 3);
    }

    #pragma unroll
    for (int kt = 1; kt < 3; ++kt) {
      const bh8 bf = *reinterpret_cast<const bh8*>(xw + ((kt * 32 + g * 8) ^ sw));
      #pragma unroll
      for (int mt = 0; mt < 6; ++mt) {
        const bh8 af = *reinterpret_cast<const bh8*>(dwp + ((mt * 3 + kt) << 9));
        dacc[mt] = __builtin_amdgcn_mfma_f32_16x16x32_bf16(af, bf, dacc[mt], 0, 0, 0);
      }
    }
    float mean2, rs2;
    ln96(dacc, mean2, rs2);
    const float da = stg[385];
    const float win = stg[386];
    #pragma unroll
    for (int mt = 0; mt < 6; ++mt)
      #pragma unroll
      for (int r = 0; r < 4; ++r) {
        float x = (dacc[mt][r] - mean2) * rs2;
        x = (x >= 0.f) ? x : da * x;
        macc[mt][r] = fmaf(win, x, macc[mt][r]);
      }
  }

  // ---- mix loads (cached; residual re-read hits L1/L2) ----
  float mxf[24];
  #pragma unroll
  for (int kt = 0; kt < 3; ++kt)
    #pragma unroll
    for (int j = 0; j < 8; ++j) mxf[kt * 8 + j] = mxL[(kt * 32 + g * 8 + j) * FT];

  // ---- merged -> XT ----
  #pragma unroll
  for (int mt = 0; mt < 6; ++mt) {
    uint2 u;
    u.x = pk2(macc[mt][0] * winv, macc[mt][1] * winv);
    u.y = pk2(macc[mt][2] * winv, macc[mt][3] * winv);
    *reinterpret_cast<uint2*>(xw + ((mt * 16 + g * 4) ^ sw)) = u;
  }
  LDSWAIT;
  bh8 gfr[3];
  #pragma unroll
  for (int kt = 0; kt < 3; ++kt) gfr[kt] = *reinterpret_cast<const bh8*>(xw + ((kt * 32 + g * 8) ^ sw));

  bh8 mxb[3];
  #pragma unroll
  for (int kt = 0; kt < 3; ++kt)
    #pragma unroll
    for (int j = 0; j < 8; ++j) mxb[kt][j] = (short)b16u(mxf[kt * 8 + j]);

  const float* stQ = stage + (nb << 9);

  // ---- Q: kt0 from pre; refill pre <- K g0 ----
  f4 qacc[6];
  init6(qacc, stQ, oo);
  const unsigned short* qp16 = q16 + lb;
  #pragma unroll
  for (int mt = 0; mt < 6; ++mt)
    qacc[mt] = __builtin_amdgcn_mfma_f32_16x16x32_bf16(pre[mt], mxb[0], qacc[mt], 0, 0, 0);
  load6s(pre, k16 + lb, 3);
  #pragma unroll
  for (int kt = 1; kt < 3; ++kt)
    #pragma unroll
    for (int mt = 0; mt < 6; ++mt) {
      const bh8 af = *reinterpret_cast<const bh8*>(qp16 + ((mt * 3 + kt) << 9));
      qacc[mt] = __builtin_amdgcn_mfma_f32_16x16x32_bf16(af, mxb[kt], qacc[mt], 0, 0, 0);
    }
  // ---- K: kt0 from pre; refill pre <- V g0 ----
  f4 kacc[6];
  init6(kacc, stQ + 96, oo);
  const unsigned short* kp16 = k16 + lb;
  #pragma unroll
  for (int mt = 0; mt < 6; ++mt)
    kacc[mt] = __builtin_amdgcn_mfma_f32_16x16x32_bf16(pre[mt], gfr[0], kacc[mt], 0, 0, 0);
  load6s(pre, v16 + lb, 3);
  #pragma unroll
  for (int kt = 1; kt < 3; ++kt)
    #pragma unroll
    for (int mt = 0; mt < 6; ++mt) {
      const bh8 af = *reinterpret_cast<const bh8*>(kp16 + ((mt * 3 + kt) << 9));
      kacc[mt] = __builtin_amdgcn_mfma_f32_16x16x32_bf16(af, gfr[kt], kacc[mt], 0, 0, 0);
    }
  float p = 0.f;
  #pragma unroll
  for (int mt = 0; mt < 6; ++mt)
    #pragma unroll
    for (int r = 0; r < 4; ++r) p = fmaf(qacc[mt][r], kacc[mt][r], p);
  p += __shfl_xor(p, 16); p += __shfl_xor(p, 32);
  const float sig = 1.f / (1.f + __expf(-p * 0.10206207261596575f));

  // ---- V: kt0 from pre; refill pre <- O g0 ----
  f4 vacc[6];
  init6(vacc, stQ + 192, oo);
  const unsigned short* vp16 = v16 + lb;
  #pragma unroll
  for (int mt = 0; mt < 6; ++mt)
    vacc[mt] = __builtin_amdgcn_mfma_f32_16x16x32_bf16(pre[mt], gfr[0], vacc[mt], 0, 0, 0);
  load6s(pre, o16 + lb, 3);
  #pragma unroll
  for (int kt = 1; kt < 3; ++kt)
    #pragma unroll
    for (int mt = 0; mt < 6; ++mt) {
      const bh8 af = *reinterpret_cast<const bh8*>(vp16 + ((mt * 3 + kt) << 9));
      vacc[mt] = __builtin_amdgcn_mfma_f32_16x16x32_bf16(af, gfr[kt], vacc[mt], 0, 0, 0);
    }
  #pragma unroll
  for (int mt = 0; mt < 6; ++mt) {
    uint2 u;
    u.x = pk2(vacc[mt][0] * sig, vacc[mt][1] * sig);
    u.y = pk2(vacc[mt][2] * sig, vacc[mt][3] * sig);
    *reinterpret_cast<uint2*>(xw + ((mt * 16 + g * 4) ^ sw)) = u;
  }
  // residual loads issue before the wait
  float mres[6][4];
  #pragma unroll
  for (int mt = 0; mt < 6; ++mt)
    #pragma unroll
    for (int r = 0; r < 4; ++r) mres[mt][r] = mxL[(mt * 16 + g * 4 + r) * FT];
  LDSWAIT;
  bh8 afr[3];
  #pragma unroll
  for (int kt = 0; kt < 3; ++kt) afr[kt] = *reinterpret_cast<const bh8*>(xw + ((kt * 32 + g * 8) ^ sw));

  // ---- O: kt0 from pre; results -> OS staging (f32, stride 65) ----
  f4 oacc[6];
  init6(oacc, stQ + 288, oo);
  const unsigned short* op16 = o16 + lb;
  #pragma unroll
  for (int mt = 0; mt < 6; ++mt)
    oacc[mt] = __builtin_amdgcn_mfma_f32_16x16x32_bf16(pre[mt], afr[0], oacc[mt], 0, 0, 0);
  #pragma unroll
  for (int kt = 1; kt < 3; ++kt)
    #pragma unroll
    for (int mt = 0; mt < 6; ++mt) {
      const bh8 af = *reinterpret_cast<const bh8*>(op16 + ((mt * 3 + kt) << 9));
      oacc[mt] = __builtin_amdgcn_mfma_f32_16x16x32_bf16(af, afr[kt], oacc[mt], 0, 0, 0);
    }
  #pragma unroll
  for (int mt = 0; mt < 6; ++mt)
    #pragma unroll
    for (int r = 0; r < 4; ++r)
      OS[(mt * 16 + g * 4 + r) * 65 + col] = mres[mt][r] + oacc[mt][r];

  __syncthreads();   // all waves' OS writes visible

  // ---- block-coalesced full-line NT stores: each wave = one 256B row-segment ----
  const int cvalid = 1000 - t0;   // valid columns in this tile
  #pragma unroll
  for (int it = 0; it < 24; ++it) {
    const int i   = it * 256 + tid;
    const int row = i >> 6;
    const int c   = i & 63;
    const float val = OS[row * 65 + c];
    if (c < cvalid)
      __builtin_nontemporal_store(val, out + (b * 96 + row) * FT + f * 1000 + t0 + c);
  }
}

extern "C" void kernel_launch(void* const* d_in, const int* in_sizes, int n_in,
                              void* d_out, int out_size, void* d_ws, size_t ws_size,
                              hipStream_t stream) {
  (void)in_sizes; (void)n_in; (void)out_size; (void)ws_size;
  const float* mix   = (const float*)d_in[0];
  const float* spin  = (const float*)d_in[1];
  const float* doa   = (const float*)d_in[2];
  const float* enc_w = (const float*)d_in[3];
  const float* enc_b = (const float*)d_in[4];
  const float* enc_a = (const float*)d_in[5];
  const float* dqg_w = (const float*)d_in[6];
  const float* dqg_b = (const float*)d_in[7];
  const float* dec_w = (const float*)d_in[8];
  const float* dec_b = (const float*)d_in[9];
  const float* dec_a = (const float*)d_in[10];
  const float* qw    = (const float*)d_in[11];
  const float* qb    = (const float*)d_in[12];
  const float* kw    = (const float*)d_in[13];
  const float* kb    = (const float*)d_in[14];
  const float* vw    = (const float*)d_in[15];
  const float* vb    = (const float*)d_in[16];
  const float* oww   = (const float*)d_in[17];
  const float* obb   = (const float*)d_in[18];
  float* outp = (float*)d_out;

  unsigned short* w16 = (unsigned short*)d_ws;
  unsigned short* enc16 = w16;                 // 31*6144
  unsigned short* dec16 = w16 + 190464;        // 31*9216
  unsigned short* q16   = w16 + 476160;
  unsigned short* k16   = q16 + 9216;
  unsigned short* v16   = k16 + 9216;
  unsigned short* o16   = v16 + 9216;
  float* gbws = (float*)((char*)d_ws + 1026048);  // 31*4*192 f32 (95232 B)
  float* ftab = (float*)((char*)d_ws + 1121280);  // 257*8 f32 (8224 B)

  hipLaunchKernelGGL(prep_w, dim3(512), dim3(256), 0, stream,
                     enc_w, dec_w, qw, kw, vw, oww, w16);
  hipLaunchKernelGGL(qp_kernel, dim3(NBANDS, 4), dim3(192), 0, stream,
                     doa, dqg_w, dqg_b, gbws);
  hipLaunchKernelGGL(tab_kernel, dim3(1), dim3(320), 0, stream, ftab);
  hipLaunchKernelGGL(fused_mfma, dim3(16448), dim3(256), 0, stream,
                     mix, spin, enc16, enc_b, enc_a, dec16, dec_b, dec_a, gbws, ftab,
                     q16, qb, k16, kb, v16, vb, o16, obb, outp);
}

// Round 13
// 541.672 us; speedup vs baseline: 1.2403x; 1.0213x over previous
//
#include <hip/hip_runtime.h>
#include <math.h>

#define NBANDS 31
#define FT 257000

typedef __attribute__((ext_vector_type(8))) short bh8;
typedef __attribute__((ext_vector_type(4))) float f4;

__constant__ int d_bs[NBANDS] = {0,1,1,2,2,2,3,3,4,5,6,7,8,10,11,13,16,19,23,27,32,38,45,54,64,76,91,108,128,152,181};
__constant__ int d_be[NBANDS] = {2,3,3,3,4,4,5,6,7,8,9,11,12,14,17,20,24,28,33,39,46,55,65,77,92,109,129,153,182,216,257};

__device__ __forceinline__ unsigned short b16u(float v) {
  __bf16 h = (__bf16)v;
  return __builtin_bit_cast(unsigned short, h);
}
__device__ __forceinline__ unsigned pk2(float a, float b) {
  return (unsigned)b16u(a) | ((unsigned)b16u(b) << 16);
}
__device__ __forceinline__ float hann1(int i, int L) {
  return 0.5f - 0.5f * cosf(6.283185307179586f * (float)i / (float)L);
}

// ---- weight f32 -> bf16 prep, permuted into MFMA-fragment order ----
__global__ __launch_bounds__(256) void prep_w(
    const float* __restrict__ enc_w, const float* __restrict__ dec_w,
    const float* __restrict__ qw, const float* __restrict__ kw,
    const float* __restrict__ vw, const float* __restrict__ ow,
    unsigned short* __restrict__ w16) {
  const int stride = gridDim.x * blockDim.x;
  for (int i = blockIdx.x * blockDim.x + threadIdx.x; i < 513024; i += stride) {
    float v;
    if (i < 190464) {                      // enc: K=64, KT=2
      const int k = i / 6144, r = i - k * 6144;
      const int tile = r >> 9, li = r & 511;
      const int lane = li >> 3, j = li & 7;
      const int g = lane >> 4, n = lane & 15;
      const int mt = tile >> 1, kt = tile & 1;
      v = enc_w[k * 6144 + (mt * 16 + n) * 64 + kt * 32 + g * 8 + j];
    } else if (i < 476160) {               // dec: K=96, KT=3
      const int i2 = i - 190464;
      const int k = i2 / 9216, r = i2 - k * 9216;
      const int tile = r >> 9, li = r & 511;
      const int lane = li >> 3, j = li & 7;
      const int g = lane >> 4, n = lane & 15;
      const int mt = tile / 3, kt = tile - mt * 3;
      v = dec_w[k * 9216 + (mt * 16 + n) * 96 + kt * 32 + g * 8 + j];
    } else {                               // q,k,v,o
      const int i2 = i - 476160;
      const int a = i2 / 9216, r = i2 - a * 9216;
      const int tile = r >> 9, li = r & 511;
      const int lane = li >> 3, j = li & 7;
      const int g = lane >> 4, n = lane & 15;
      const int mt = tile / 3, kt = tile - mt * 3;
      const float* src = (a == 0) ? qw : (a == 1) ? kw : (a == 2) ? vw : ow;
      v = src[(mt * 16 + n) * 96 + kt * 32 + g * 8 + j];
    }
    w16[i] = b16u(v);
  }
}

__global__ __launch_bounds__(192) void qp_kernel(const float* __restrict__ doa,
                                                 const float* __restrict__ dqg_w,
                                                 const float* __restrict__ dqg_b,
                                                 float* __restrict__ gbuf) {
  const int k = blockIdx.x, b = blockIdx.y;
  const int tid = threadIdx.x;
  __shared__ float sdoa[36];
  if (tid < 36) sdoa[tid] = doa[b * 36 + tid];
  __syncthreads();
  const float* wr = dqg_w + (k * 192 + tid) * 36;
  float acc = dqg_b[k * 192 + tid];
  #pragma unroll
  for (int i = 0; i < 36; ++i) acc = fmaf(wr[i], sdoa[i], acc);
  if (tid < 96) acc += 1.0f;
  gbuf[(k * 4 + b) * 192 + tid] = acc;
}

// ---- per-f table: {k0, nb, winv, win0..win4} ----
__global__ __launch_bounds__(320) void tab_kernel(float* __restrict__ ftab) {
  const int f = blockIdx.x * blockDim.x + threadIdx.x;
  if (f >= 257) return;
  int k0 = 0; while (d_be[k0] <= f) ++k0;
  int k1 = k0; while (k1 < NBANDS && d_bs[k1] <= f) ++k1;
  float wsum = 0.f, wn[5];
  for (int k = k0; k < k1; ++k) {
    const float wv = hann1(f - d_bs[k], d_be[k] - d_bs[k]);
    wn[k - k0] = wv; wsum += wv;
  }
  float* o = ftab + f * 8;
  o[0] = (float)k0; o[1] = (float)(k1 - k0); o[2] = 1.0f / fmaxf(wsum, 1e-8f);
  #pragma unroll
  for (int j = 0; j < 5; ++j) o[3 + j] = (j < k1 - k0) ? wn[j] : 0.f;
}

#define LDSWAIT asm volatile("s_waitcnt lgkmcnt(0)" ::: "memory")

__device__ __forceinline__ void init6(f4* acc, const float* s, int off) {
  #pragma unroll
  for (int mt = 0; mt < 6; ++mt) {
    const float4 bb = *reinterpret_cast<const float4*>(s + mt * 16 + off);
    acc[mt] = (f4){bb.x, bb.y, bb.z, bb.w};
  }
}
// tree-reduced LN over 24 per-lane values (+16/+32 shfl for 96-chan column)
__device__ __forceinline__ void ln96(const f4* acc, float& mean, float& rs) {
  float s0 = 0.f, s1 = 0.f, s2 = 0.f, s3 = 0.f;
  float q0 = 0.f, q1 = 0.f, q2 = 0.f, q3 = 0.f;
  #pragma unroll
  for (int mt = 0; mt < 6; ++mt) {
    const float a0 = acc[mt][0], a1 = acc[mt][1], a2 = acc[mt][2], a3 = acc[mt][3];
    s0 += a0; s1 += a1; s2 += a2; s3 += a3;
    q0 = fmaf(a0, a0, q0); q1 = fmaf(a1, a1, q1);
    q2 = fmaf(a2, a2, q2); q3 = fmaf(a3, a3, q3);
  }
  float sm = (s0 + s1) + (s2 + s3);
  float sq = (q0 + q1) + (q2 + q3);
  sm += __shfl_xor(sm, 16); sm += __shfl_xor(sm, 32);
  sq += __shfl_xor(sq, 16); sq += __shfl_xor(sq, 32);
  mean = sm * (1.f / 96.f);
  rs = rsqrtf(sq * (1.f / 96.f) - mean * mean + 1e-5f);
}
__device__ __forceinline__ void load6s(bh8* dst, const unsigned short* p, int step9) {
  #pragma unroll
  for (int mt = 0; mt < 6; ++mt)
    dst[mt] = *reinterpret_cast<const bh8*>(p + ((mt * step9) << 9));
}

// ---- fused MFMA kernel; aliased LDS (XT+stage / OS) -> 5 blocks/CU ----
__global__ __launch_bounds__(256, 3) void fused_mfma(
    const float* __restrict__ mix, const float* __restrict__ spin,
    const unsigned short* __restrict__ enc16, const float* __restrict__ enc_b, const float* __restrict__ enc_a,
    const unsigned short* __restrict__ dec16, const float* __restrict__ dec_b, const float* __restrict__ dec_a,
    const float* __restrict__ gb, const float* __restrict__ ftab,
    const unsigned short* __restrict__ q16, const float* __restrict__ qb,
    const unsigned short* __restrict__ k16, const float* __restrict__ kb,
    const unsigned short* __restrict__ v16, const float* __restrict__ vb,
    const unsigned short* __restrict__ o16, const float* __restrict__ ob,
    float* __restrict__ out) {
  const int id0 = (int)blockIdx.x;
  const int id  = (id0 & 7) * 2056 + (id0 >> 3);   // bijective XCD swizzle (16448 = 8*2056)
  const int tt  = id & 15;
  const int fb  = id >> 4;
  const int f   = fb % 257;
  const int b   = fb / 257;
  const int t0  = tt << 6;

  const int tid  = threadIdx.x;
  const int lane = tid & 63;
  const int w    = tid >> 6;
  const int g    = lane >> 4;
  const int n    = lane & 15;
  const int col  = (w << 4) + n;
  const int t    = t0 + col;
  const bool tv  = t < 1000;
  const int tcl  = tv ? t : 999;
  const int sw   = (n & 7) << 3;
  const int lb   = lane << 3;

  // one LDS pool: [XT 16384B][stage 11776B]; OS (96*65*4=24960B) aliases from 0
  __shared__ __align__(16) char smem[28160];
  unsigned short* XT = (unsigned short*)smem;
  float* stage = (float*)(smem + 16384);
  float* OS = (float*)smem;
  unsigned short* xw = XT + col * 128;

  const float* ft = ftab + f * 8;
  const int k0 = (int)ft[0];
  const int nb = (int)ft[1];
  const float winv = ft[2];

  // cooperative stage: per band (stride 512): encB96|decB96|gb192|ea,da,win ; tail: qb|kb|vb|ob
  {
    const int tot = (nb << 9) + 384;
    for (int i = tid; i < tot; i += 256) {
      const int kk = i >> 9, r = i & 511;
      float v = 0.f;
      if (kk < nb) {
        const int k = k0 + kk;
        if      (r < 96)  v = enc_b[k * 96 + r];
        else if (r < 192) v = dec_b[k * 96 + (r - 96)];
        else if (r < 384) v = gb[(k * 4 + b) * 192 + (r - 192)];
        else if (r == 384) v = enc_a[k];
        else if (r == 385) v = dec_a[k];
        else if (r == 386) v = ft[3 + kk];
      } else {
        const int r2 = i - (nb << 9);
        v = (r2 < 96) ? qb[r2] : (r2 < 192) ? kb[r2 - 96] : (r2 < 288) ? vb[r2 - 192] : ob[r2 - 288];
      }
      stage[i] = v;
    }
  }

  const float* spL = spin + b * 64 * FT + f * 1000 + tcl;
  const float* mxL = mix  + b * 96 * FT + f * 1000 + tcl;

  // spin prefetch (read-once)
  bh8 spb[2];
  {
    float spf[16];
    #pragma unroll
    for (int j = 0; j < 8; ++j) spf[j]     = __builtin_nontemporal_load(spL + (g * 8 + j) * FT);
    #pragma unroll
    for (int j = 0; j < 8; ++j) spf[8 + j] = __builtin_nontemporal_load(spL + (32 + g * 8 + j) * FT);
    #pragma unroll
    for (int kt = 0; kt < 2; ++kt)
      #pragma unroll
      for (int j = 0; j < 8; ++j) spb[kt][j] = (short)b16u(spf[kt * 8 + j]);
  }

  // rotating prefetch buffer: enc g0 of first band
  bh8 pre[6];
  load6s(pre, enc16 + k0 * 6144 + lb, 2);

  __syncthreads();   // stage visible

  f4 macc[6];
  #pragma unroll
  for (int mt = 0; mt < 6; ++mt) macc[mt] = (f4){0.f, 0.f, 0.f, 0.f};

  const int oo = g * 4;

  // ---------------- band loop; INV: pre = enc g0(k) at entry ----------------
  for (int kk = 0; kk < nb; ++kk) {
    const int k = k0 + kk;
    const unsigned short* ew  = enc16 + k * 6144 + lb;
    const unsigned short* dwp = dec16 + k * 9216 + lb;
    const float* stg = stage + (kk << 9);

    // ---- enc: 96x64; kt=0 from pre, kt=1 inline ----
    f4 acc[6];
    init6(acc, stg, oo);
    #pragma unroll
    for (int mt = 0; mt < 6; ++mt)
      acc[mt] = __builtin_amdgcn_mfma_f32_16x16x32_bf16(pre[mt], spb[0], acc[mt], 0, 0, 0);
    #pragma unroll
    for (int mt = 0; mt < 6; ++mt) {
      const bh8 af = *reinterpret_cast<const bh8*>(ew + ((mt * 2 + 1) << 9));
      acc[mt] = __builtin_amdgcn_mfma_f32_16x16x32_bf16(af, spb[1], acc[mt], 0, 0, 0);
    }

    // pre dead -> refill with dec g0 (hides under LN1/FiLM)
    load6s(pre, dwp, 3);

    float mean, rs;
    ln96(acc, mean, rs);
    const float ea = stg[384];
    #pragma unroll
    for (int mt = 0; mt < 6; ++mt) {
      const float4 ga = *reinterpret_cast<const float4*>(stg + 192 + mt * 16 + oo);
      const float4 be = *reinterpret_cast<const float4*>(stg + 288 + mt * 16 + oo);
      float x0 = (acc[mt][0] - mean) * rs; x0 = (x0 >= 0.f) ? x0 : ea * x0;
      float x1 = (acc[mt][1] - mean) * rs; x1 = (x1 >= 0.f) ? x1 : ea * x1;
      float x2 = (acc[mt][2] - mean) * rs; x2 = (x2 >= 0.f) ? x2 : ea * x2;
      float x3 = (acc[mt][3] - mean) * rs; x3 = (x3 >= 0.f) ? x3 : ea * x3;
      uint2 u;
      u.x = pk2(fmaf(ga.x, x0, be.x), fmaf(ga.y, x1, be.y));
      u.y = pk2(fmaf(ga.z, x2, be.z), fmaf(ga.w, x3, be.w));
      *reinterpret_cast<uint2*>(xw + ((mt * 16 + g * 4) ^ sw)) = u;
    }
    LDSWAIT;

    // ---- dec: 96x96 from XT; kt=0 from pre ----
    f4 dacc[6];
    init6(dacc, stg + 96, oo);
    {
      const bh8 bf0 = *reinterpret_cast<const bh8*>(xw + ((0 * 32 + g * 8) ^ sw));
      #pragma unroll
      for (int mt = 0; mt < 6; ++mt)
        dacc[mt] = __builtin_amdgcn_mfma_f32_16x16x32_bf16(pre[mt], bf0, dacc[mt], 0, 0, 0);
    }

    // pre dead -> refill with next band's enc g0 (or Q g0)
    {
      const bool more = (kk + 1 < nb);
      load6s(pre, more ? (enc16 + (k + 1) * 6144 + lb) : (q16 + lb), more ? 2 : 3);
    }

    #pragma unroll
    for (int kt = 1; kt < 3; ++kt) {
      const bh8 bf = *reinterpret_cast<const bh8*>(xw + ((kt * 32 + g * 8) ^ sw));
      #pragma unroll
      for (int mt = 0; mt < 6; ++mt) {
        const bh8 af = *reinterpret_cast<const bh8*>(dwp + ((mt * 3 + kt) << 9));
        dacc[mt] = __builtin_amdgcn_mfma_f32_16x16x32_bf16(af, bf, dacc[mt], 0, 0, 0);
      }
    }
    float mean2, rs2;
    ln96(dacc, mean2, rs2);
    const float da = stg[385];
    const float win = stg[386];
    #pragma unroll
    for (int mt = 0; mt < 6; ++mt)
      #pragma unroll
      for (int r = 0; r < 4; ++r) {
        float x = (dacc[mt][r] - mean2) * rs2;
        x = (x >= 0.f) ? x : da * x;
        macc[mt][r] = fmaf(win, x, macc[mt][r]);
      }
  }

  // ---- mix loads (cached; residual re-read hits L1/L2) ----
  float mxf[24];
  #pragma unroll
  for (int kt = 0; kt < 3; ++kt)
    #pragma unroll
    for (int j = 0; j < 8; ++j) mxf[kt * 8 + j] = mxL[(kt * 32 + g * 8 + j) * FT];

  // ---- merged -> XT ----
  #pragma unroll
  for (int mt = 0; mt < 6; ++mt) {
    uint2 u;
    u.x = pk2(macc[mt][0] * winv, macc[mt][1] * winv);
    u.y = pk2(macc[mt][2] * winv, macc[mt][3] * winv);
    *reinterpret_cast<uint2*>(xw + ((mt * 16 + g * 4) ^ sw)) = u;
  }
  LDSWAIT;
  bh8 gfr[3];
  #pragma unroll
  for (int kt = 0; kt < 3; ++kt) gfr[kt] = *reinterpret_cast<const bh8*>(xw + ((kt * 32 + g * 8) ^ sw));

  bh8 mxb[3];
  #pragma unroll
  for (int kt = 0; kt < 3; ++kt)
    #pragma unroll
    for (int j = 0; j < 8; ++j) mxb[kt][j] = (short)b16u(mxf[kt * 8 + j]);

  const float* stQ = stage + (nb << 9);

  // ---- Q: kt0 from pre; refill pre <- K g0 ----
  f4 qacc[6];
  init6(qacc, stQ, oo);
  const unsigned short* qp16 = q16 + lb;
  #pragma unroll
  for (int mt = 0; mt < 6; ++mt)
    qacc[mt] = __builtin_amdgcn_mfma_f32_16x16x32_bf16(pre[mt], mxb[0], qacc[mt], 0, 0, 0);
  load6s(pre, k16 + lb, 3);
  #pragma unroll
  for (int kt = 1; kt < 3; ++kt)
    #pragma unroll
    for (int mt = 0; mt < 6; ++mt) {
      const bh8 af = *reinterpret_cast<const bh8*>(qp16 + ((mt * 3 + kt) << 9));
      qacc[mt] = __builtin_amdgcn_mfma_f32_16x16x32_bf16(af, mxb[kt], qacc[mt], 0, 0, 0);
    }
  // ---- K: kt0 from pre; refill pre <- V g0 ----
  f4 kacc[6];
  init6(kacc, stQ + 96, oo);
  const unsigned short* kp16 = k16 + lb;
  #pragma unroll
  for (int mt = 0; mt < 6; ++mt)
    kacc[mt] = __builtin_amdgcn_mfma_f32_16x16x32_bf16(pre[mt], gfr[0], kacc[mt], 0, 0, 0);
  load6s(pre, v16 + lb, 3);
  #pragma unroll
  for (int kt = 1; kt < 3; ++kt)
    #pragma unroll
    for (int mt = 0; mt < 6; ++mt) {
      const bh8 af = *reinterpret_cast<const bh8*>(kp16 + ((mt * 3 + kt) << 9));
      kacc[mt] = __builtin_amdgcn_mfma_f32_16x16x32_bf16(af, gfr[kt], kacc[mt], 0, 0, 0);
    }
  float p0 = 0.f, p1 = 0.f;
  #pragma unroll
  for (int mt = 0; mt < 6; ++mt) {
    p0 = fmaf(qacc[mt][0], kacc[mt][0], p0);
    p1 = fmaf(qacc[mt][1], kacc[mt][1], p1);
    p0 = fmaf(qacc[mt][2], kacc[mt][2], p0);
    p1 = fmaf(qacc[mt][3], kacc[mt][3], p1);
  }
  float p = p0 + p1;
  p += __shfl_xor(p, 16); p += __shfl_xor(p, 32);
  const float sig = 1.f / (1.f + __expf(-p * 0.10206207261596575f));

  // ---- V: kt0 from pre; refill pre <- O g0 ----
  f4 vacc[6];
  init6(vacc, stQ + 192, oo);
  const unsigned short* vp16 = v16 + lb;
  #pragma unroll
  for (int mt = 0; mt < 6; ++mt)
    vacc[mt] = __builtin_amdgcn_mfma_f32_16x16x32_bf16(pre[mt], gfr[0], vacc[mt], 0, 0, 0);
  load6s(pre, o16 + lb, 3);
  #pragma unroll
  for (int kt = 1; kt < 3; ++kt)
    #pragma unroll
    for (int mt = 0; mt < 6; ++mt) {
      const bh8 af = *reinterpret_cast<const bh8*>(vp16 + ((mt * 3 + kt) << 9));
      vacc[mt] = __builtin_amdgcn_mfma_f32_16x16x32_bf16(af, gfr[kt], vacc[mt], 0, 0, 0);
    }
  #pragma unroll
  for (int mt = 0; mt < 6; ++mt) {
    uint2 u;
    u.x = pk2(vacc[mt][0] * sig, vacc[mt][1] * sig);
    u.y = pk2(vacc[mt][2] * sig, vacc[mt][3] * sig);
    *reinterpret_cast<uint2*>(xw + ((mt * 16 + g * 4) ^ sw)) = u;
  }
  // residual loads issue before the wait
  float mres[6][4];
  #pragma unroll
  for (int mt = 0; mt < 6; ++mt)
    #pragma unroll
    for (int r = 0; r < 4; ++r) mres[mt][r] = mxL[(mt * 16 + g * 4 + r) * FT];
  LDSWAIT;
  bh8 afr[3];
  #pragma unroll
  for (int kt = 0; kt < 3; ++kt) afr[kt] = *reinterpret_cast<const bh8*>(xw + ((kt * 32 + g * 8) ^ sw));

  // ---- O: kt0 from pre ----
  f4 oacc[6];
  init6(oacc, stQ + 288, oo);
  const unsigned short* op16 = o16 + lb;
  #pragma unroll
  for (int mt = 0; mt < 6; ++mt)
    oacc[mt] = __builtin_amdgcn_mfma_f32_16x16x32_bf16(pre[mt], afr[0], oacc[mt], 0, 0, 0);
  #pragma unroll
  for (int kt = 1; kt < 3; ++kt)
    #pragma unroll
    for (int mt = 0; mt < 6; ++mt) {
      const bh8 af = *reinterpret_cast<const bh8*>(op16 + ((mt * 3 + kt) << 9));
      oacc[mt] = __builtin_amdgcn_mfma_f32_16x16x32_bf16(af, afr[kt], oacc[mt], 0, 0, 0);
    }

  __syncthreads();   // ALL waves done with XT/stage before aliased OS writes

  #pragma unroll
  for (int mt = 0; mt < 6; ++mt)
    #pragma unroll
    for (int r = 0; r < 4; ++r)
      OS[(mt * 16 + g * 4 + r) * 65 + col] = mres[mt][r] + oacc[mt][r];

  __syncthreads();   // all waves' OS writes visible

  // ---- block-coalesced full-line NT stores: each iteration = 4 full rows ----
  const int cvalid = 1000 - t0;   // valid columns in this tile
  #pragma unroll
  for (int it = 0; it < 24; ++it) {
    const int i   = it * 256 + tid;
    const int row = i >> 6;
    const int c   = i & 63;
    const float val = OS[row * 65 + c];
    if (c < cvalid)
      __builtin_nontemporal_store(val, out + (b * 96 + row) * FT + f * 1000 + t0 + c);
  }
}

extern "C" void kernel_launch(void* const* d_in, const int* in_sizes, int n_in,
                              void* d_out, int out_size, void* d_ws, size_t ws_size,
                              hipStream_t stream) {
  (void)in_sizes; (void)n_in; (void)out_size; (void)ws_size;
  const float* mix   = (const float*)d_in[0];
  const float* spin  = (const float*)d_in[1];
  const float* doa   = (const float*)d_in[2];
  const float* enc_w = (const float*)d_in[3];
  const float* enc_b = (const float*)d_in[4];
  const float* enc_a = (const float*)d_in[5];
  const float* dqg_w = (const float*)d_in[6];
  const float* dqg_b = (const float*)d_in[7];
  const float* dec_w = (const float*)d_in[8];
  const float* dec_b = (const float*)d_in[9];
  const float* dec_a = (const float*)d_in[10];
  const float* qw    = (const float*)d_in[11];
  const float* qb    = (const float*)d_in[12];
  const float* kw    = (const float*)d_in[13];
  const float* kb    = (const float*)d_in[14];
  const float* vw    = (const float*)d_in[15];
  const float* vb    = (const float*)d_in[16];
  const float* oww   = (const float*)d_in[17];
  const float* obb   = (const float*)d_in[18];
  float* outp = (float*)d_out;

  unsigned short* w16 = (unsigned short*)d_ws;
  unsigned short* enc16 = w16;                 // 31*6144
  unsigned short* dec16 = w16 + 190464;        // 31*9216
  unsigned short* q16   = w16 + 476160;
  unsigned short* k16   = q16 + 9216;
  unsigned short* v16   = k16 + 9216;
  unsigned short* o16   = v16 + 9216;
  float* gbws = (float*)((char*)d_ws + 1026048);  // 31*4*192 f32 (95232 B)
  float* ftab = (float*)((char*)d_ws + 1121280);  // 257*8 f32 (8224 B)

  hipLaunchKernelGGL(prep_w, dim3(512), dim3(256), 0, stream,
                     enc_w, dec_w, qw, kw, vw, oww, w16);
  hipLaunchKernelGGL(qp_kernel, dim3(NBANDS, 4), dim3(192), 0, stream,
                     doa, dqg_w, dqg_b, gbws);
  hipLaunchKernelGGL(tab_kernel, dim3(1), dim3(320), 0, stream, ftab);
  hipLaunchKernelGGL(fused_mfma, dim3(16448), dim3(256), 0, stream,
                     mix, spin, enc16, enc_b, enc_a, dec16, dec_b, dec_a, gbws, ftab,
                     q16, qb, k16, kb, v16, vb, o16, obb, outp);
}